// Round 1
// baseline (297.947 us; speedup 1.0000x reference)
//
#include <hip/hip_runtime.h>
#include <stdint.h>

// VanillaRNN fused: B=2048,S=125,I=2,H=300,O=2
// h_{t} = relu(x_t@W_ih^T + b_ih + h_{t-1}@W_hh^T + b_hh) + 0.01*noise_t
// out   = h_t @ W_out^T + b_out
//
// 128 workgroups x 640 threads (10 waves). Each WG owns 16 batch rows for all
// 125 steps (rows are independent -> no inter-WG sync). Each wave owns 32 of
// the 320 (padded) hidden columns; its W_hh^T fragments are loaded ONCE into
// 80 VGPRs and reused for all steps. h round-trips through LDS as bf16.

#define SEQ   125
#define HID   300
#define NPAD  320
#define APAD  328   // LDS row stride in bf16: 328*2=656B, 656/4 mod 32 = 4 -> conflict-light
#define KT    10    // k-tiles of 32
#define WAVES 10
#define NTH   640

typedef __attribute__((ext_vector_type(8))) short bf16x8;
typedef __attribute__((ext_vector_type(4))) float f32x4;

__device__ __forceinline__ short f2bf(float f) {
  union { float f; uint32_t u; } v; v.f = f;
  uint32_t r = (v.u + 0x7fffu + ((v.u >> 16) & 1u)) >> 16;  // RNE
  return (short)r;
}

__global__ __launch_bounds__(NTH) void rnn_fused(
    const float* __restrict__ x,      // [2048,125,2]
    const float* __restrict__ noise,  // [2048,125,300]
    const float* __restrict__ W_ih,   // [300,2]
    const float* __restrict__ b_ih,   // [300]
    const float* __restrict__ W_hh,   // [300,300]
    const float* __restrict__ b_hh,   // [300]
    const float* __restrict__ W_out,  // [2,300]
    const float* __restrict__ b_out,  // [2]
    float* __restrict__ out)          // [2048,125,2]
{
  __shared__ __align__(16) short Abuf[2][16][APAD];   // h (bf16), double-buffered
  __shared__ float part[2][WAVES][16][2];             // per-wave out partials
  __shared__ float outbuf[16][SEQ * 2];               // staged outputs

  const int tid  = threadIdx.x;
  const int wave = tid >> 6;
  const int lane = tid & 63;
  const int grp  = lane >> 4;   // 0..3
  const int lc   = lane & 15;   // 0..15
  const int row0 = blockIdx.x << 4;   // batch row base (16 rows per WG)
  const int n0   = wave << 5;         // this wave's hidden-column base (32 cols)

  // zero initial h buffer (h0 = 0); pad cols stay 0 forever (rewritten as 0 each step)
  for (int i = tid; i < 16 * APAD / 2; i += NTH)
    ((uint32_t*)&Abuf[0][0][0])[i] = 0u;

  // ---- per-lane column constants (col = n0 + nt*16 + lc), zeroed for pad cols ----
  float wih0[2], wih1[2], biasc[2], wo0[2], wo1[2], nsc[2];
  int ncol[2];
#pragma unroll
  for (int nt = 0; nt < 2; ++nt) {
    int c = n0 + nt * 16 + lc;
    bool vld = (c < HID);
    int cc = vld ? c : 0;
    wih0[nt]  = vld ? W_ih[cc * 2 + 0] : 0.f;
    wih1[nt]  = vld ? W_ih[cc * 2 + 1] : 0.f;
    biasc[nt] = vld ? (b_ih[cc] + b_hh[cc]) : 0.f;
    wo0[nt]   = vld ? W_out[cc] : 0.f;
    wo1[nt]   = vld ? W_out[HID + cc] : 0.f;
    nsc[nt]   = vld ? 0.01f : 0.f;
    ncol[nt]  = cc;
  }

  // ---- persistent W_hh^T fragments: B[k][n] = W_hh[n][k] ----
  // B-frag layout (16x16x32): lane holds col = lc, k = kt*32 + grp*8 + e
  bf16x8 wf[2][KT];
#pragma unroll
  for (int nt = 0; nt < 2; ++nt) {
    int n = n0 + nt * 16 + lc;
#pragma unroll
    for (int kt = 0; kt < KT; ++kt) {
      bf16x8 f;
#pragma unroll
      for (int e = 0; e < 8; ++e) {
        int k = kt * 32 + grp * 8 + e;
        float val = (n < HID && k < HID) ? W_hh[n * HID + k] : 0.f;
        f[e] = f2bf(val);
      }
      wf[nt][kt] = f;
    }
  }

  const float bout0 = b_out[0], bout1 = b_out[1];

  // incremental addresses: this lane's 4 batch rows = row0 + grp*4 + r
  int noff[2][4], xoff[4];
#pragma unroll
  for (int r = 0; r < 4; ++r) {
    int b = row0 + grp * 4 + r;
    xoff[r] = b * (SEQ * 2);
#pragma unroll
    for (int nt = 0; nt < 2; ++nt)
      noff[nt][r] = b * (SEQ * HID) + ncol[nt];
  }

  __syncthreads();

  for (int s = 0; s < SEQ; ++s) {
    const int cur = s & 1, nxt = cur ^ 1;

    // prefetch noise + x for this step (covered by the MFMA phase below)
    float nb[2][4], xr0[4], xr1[4];
#pragma unroll
    for (int r = 0; r < 4; ++r) {
      xr0[r] = x[xoff[r] + 0];
      xr1[r] = x[xoff[r] + 1];
#pragma unroll
      for (int nt = 0; nt < 2; ++nt)
        nb[nt][r] = noise[noff[nt][r]];
    }

    // ---- MFMA: acc[16 rows x 16 cols] per n-tile, K = 320 ----
    f32x4 acc0 = {0.f, 0.f, 0.f, 0.f};
    f32x4 acc1 = {0.f, 0.f, 0.f, 0.f};
#pragma unroll
    for (int kt = 0; kt < KT; ++kt) {
      bf16x8 a = *(const bf16x8*)&Abuf[cur][lc][kt * 32 + grp * 8];
      acc0 = __builtin_amdgcn_mfma_f32_16x16x32_bf16(a, wf[0][kt], acc0, 0, 0, 0);
      acc1 = __builtin_amdgcn_mfma_f32_16x16x32_bf16(a, wf[1][kt], acc1, 0, 0, 0);
    }

    // ---- epilogue: h = relu(acc + x@W_ih^T + b) + 0.01*noise ----
    // C/D layout: col = lc, row(local) = grp*4 + r
    float p0[4], p1[4];
#pragma unroll
    for (int r = 0; r < 4; ++r) {
      float pre0 = acc0[r] + xr0[r] * wih0[0] + xr1[r] * wih1[0] + biasc[0];
      float pre1 = acc1[r] + xr0[r] * wih0[1] + xr1[r] * wih1[1] + biasc[1];
      float h0v = fmaxf(pre0, 0.f) + nsc[0] * nb[0][r];
      float h1v = fmaxf(pre1, 0.f) + nsc[1] * nb[1][r];
      p0[r] = h0v * wo0[0] + h1v * wo0[1];
      p1[r] = h0v * wo1[0] + h1v * wo1[1];
      int lrow = grp * 4 + r;
      Abuf[nxt][lrow][n0 + lc]      = f2bf(h0v);
      Abuf[nxt][lrow][n0 + 16 + lc] = f2bf(h1v);
    }

    // reduce out-partials across the 16 lanes that share these 4 rows
#pragma unroll
    for (int m = 1; m < 16; m <<= 1) {
#pragma unroll
      for (int r = 0; r < 4; ++r) {
        p0[r] += __shfl_xor(p0[r], m);
        p1[r] += __shfl_xor(p1[r], m);
      }
    }
    if (lc == 0) {
#pragma unroll
      for (int r = 0; r < 4; ++r) {
        part[cur][wave][grp * 4 + r][0] = p0[r];
        part[cur][wave][grp * 4 + r][1] = p1[r];
      }
    }

    __syncthreads();

    // cross-wave reduce (32 threads) -> staged output
    if (tid < 32) {
      int rr = tid >> 1, o = tid & 1;
      float v = o ? bout1 : bout0;
#pragma unroll
      for (int w = 0; w < WAVES; ++w) v += part[cur][w][rr][o];
      outbuf[rr][s * 2 + o] = v;
    }

    // advance addresses
#pragma unroll
    for (int r = 0; r < 4; ++r) {
      xoff[r] += 2;
#pragma unroll
      for (int nt = 0; nt < 2; ++nt) noff[nt][r] += HID;
    }
  }

  __syncthreads();

  // coalesced flush of staged outputs: out[b][s][o], 250 floats per row
  {
    int r = tid / 40, c0 = tid % 40;
    for (int j = c0; j < SEQ * 2; j += 40)
      out[(row0 + r) * (SEQ * 2) + j] = outbuf[r][j];
  }
}

extern "C" void kernel_launch(void* const* d_in, const int* in_sizes, int n_in,
                              void* d_out, int out_size, void* d_ws, size_t ws_size,
                              hipStream_t stream) {
  const float* xp     = (const float*)d_in[0];
  const float* noise  = (const float*)d_in[1];
  const float* W_ih   = (const float*)d_in[2];
  const float* b_ih   = (const float*)d_in[3];
  const float* W_hh   = (const float*)d_in[4];
  const float* b_hh   = (const float*)d_in[5];
  const float* W_out  = (const float*)d_in[6];
  const float* b_out  = (const float*)d_in[7];
  float* outp         = (float*)d_out;

  rnn_fused<<<dim3(2048 / 16), dim3(NTH), 0, stream>>>(
      xp, noise, W_ih, b_ih, W_hh, b_hh, W_out, b_out, outp);
}

// Round 2
// 290.515 us; speedup vs baseline: 1.0256x; 1.0256x over previous
//
#include <hip/hip_runtime.h>
#include <stdint.h>

// VanillaRNN fused: B=2048,S=125,I=2,H=300,O=2
// h_t = relu(x_t@W_ih^T + b_ih + h_{t-1}@W_hh^T + b_hh) + 0.01*noise_t
// out = h_t @ W_out^T + b_out
//
// 256 WGs x 640 threads (10 waves); each WG owns 8 batch rows for all 125
// steps (rows independent -> no inter-WG sync; every CU gets one WG).
// Each wave owns 32 hidden columns, mapped as even/odd pairs (c0=n0+2lc,
// c1=c0+1) so each lane's two h outputs are adjacent -> packed 32b LDS
// write + float2 noise load. W_hh^T fragments persist in registers.
// Noise is prefetched one full step ahead (register double-buffer).

#define SEQ   125
#define HID   300
#define APAD  328   // LDS row stride (shorts); 656B stride -> conflict-light
#define KT    10
#define WAVES 10
#define NTH   640
#define RPW   8     // batch rows per WG

typedef __attribute__((ext_vector_type(8))) short bf16x8;
typedef __attribute__((ext_vector_type(4))) float f32x4;

__device__ __forceinline__ short f2bf(float f) {
  union { float f; uint32_t u; } v; v.f = f;
  uint32_t r = (v.u + 0x7fffu + ((v.u >> 16) & 1u)) >> 16;  // RNE
  return (short)r;
}

__global__ __launch_bounds__(NTH) void rnn_fused(
    const float* __restrict__ x,      // [2048,125,2]
    const float* __restrict__ noise,  // [2048,125,300]
    const float* __restrict__ W_ih,   // [300,2]
    const float* __restrict__ b_ih,   // [300]
    const float* __restrict__ W_hh,   // [300,300]
    const float* __restrict__ b_hh,   // [300]
    const float* __restrict__ W_out,  // [2,300]
    const float* __restrict__ b_out,  // [2]
    float* __restrict__ out)          // [2048,125,2]
{
  __shared__ __align__(16) short Abuf[2][16][APAD];  // h (bf16), dbuf; rows 8..15 stay 0
  __shared__ float xbuf[RPW][SEQ * 2];               // staged x
  __shared__ float outbuf[RPW][SEQ * 2];             // staged outputs
  __shared__ float part[2][WAVES][RPW][2];           // per-wave out partials

  const int tid  = threadIdx.x;
  const int wave = tid >> 6;
  const int lane = tid & 63;
  const int grp  = lane >> 4;   // 0..3
  const int lc   = lane & 15;   // 0..15
  const int row0 = blockIdx.x * RPW;
  const int n0   = wave << 5;          // wave's 32-col base
  const int c0   = n0 + 2 * lc;        // tile-0 col (even)
  const int c1   = c0 + 1;             // tile-1 col (odd)
  const bool v0  = (c0 < HID), v1 = (c1 < HID);
  const bool rowv = (grp < 2);         // this lane's rows (grp*4+r) valid?

  // zero both h buffers once (pad cols + rows 8..15 stay 0 forever)
  for (int i = tid; i < 2 * 16 * APAD / 2; i += NTH)
    ((uint32_t*)Abuf)[i] = 0u;
  // stage x for this WG's 8 rows
  for (int i = tid; i < RPW * SEQ * 2; i += NTH) {
    int r = i / (SEQ * 2), j = i % (SEQ * 2);
    xbuf[r][j] = x[(row0 + r) * (SEQ * 2) + j];
  }

  const int cc0 = v0 ? c0 : 0;
  const float wih00 = v0 ? W_ih[c0 * 2 + 0] : 0.f;
  const float wih10 = v0 ? W_ih[c0 * 2 + 1] : 0.f;
  const float wih01 = v1 ? W_ih[c1 * 2 + 0] : 0.f;
  const float wih11 = v1 ? W_ih[c1 * 2 + 1] : 0.f;
  const float biasc0 = v0 ? (b_ih[c0] + b_hh[c0]) : 0.f;
  const float biasc1 = v1 ? (b_ih[c1] + b_hh[c1]) : 0.f;
  const float wo00 = v0 ? W_out[c0] : 0.f;
  const float wo01 = v1 ? W_out[c1] : 0.f;
  const float wo10 = v0 ? W_out[HID + c0] : 0.f;
  const float wo11 = v1 ? W_out[HID + c1] : 0.f;
  const float nsc0 = v0 ? 0.01f : 0.f;
  const float nsc1 = v1 ? 0.01f : 0.f;

  // persistent W_hh^T fragments: wf[t][kt] lane holds W_hh[c_t][k], k=kt*32+grp*8+e
  bf16x8 wf0[KT], wf1[KT];
#pragma unroll
  for (int kt = 0; kt < KT; ++kt) {
    bf16x8 f0, f1;
#pragma unroll
    for (int e = 0; e < 8; ++e) {
      int k = kt * 32 + grp * 8 + e;
      bool kv = (k < HID);
      f0[e] = f2bf((v0 && kv) ? W_hh[c0 * HID + k] : 0.f);
      f1[e] = f2bf((v1 && kv) ? W_hh[c1 * HID + k] : 0.f);
    }
    wf0[kt] = f0; wf1[kt] = f1;
  }

  const float bout0 = b_out[0], bout1 = b_out[1];

  int nbase[4];
#pragma unroll
  for (int r = 0; r < 4; ++r) {
    int b = row0 + (grp & 1) * 4 + r;      // in-range even for invalid lanes
    nbase[r] = b * (SEQ * HID) + cc0;
  }

  // preload noise for step 0
  float2 nbA[4] = {}, nbB[4] = {};
  if (rowv) {
#pragma unroll
    for (int r = 0; r < 4; ++r)
      nbA[r] = *(const float2*)&noise[nbase[r]];
  }

  __syncthreads();

#define STEP(S, NBC, NBN)                                                      \
  {                                                                            \
    const int cur = (S) & 1, nxt = cur ^ 1;                                    \
    /* prefetch noise for step S+1: full step to hide HBM latency */           \
    if (rowv && (S) + 1 < SEQ) {                                               \
      _Pragma("unroll")                                                        \
      for (int r = 0; r < 4; ++r)                                              \
        NBN[r] = *(const float2*)&noise[nbase[r] + ((S) + 1) * HID];           \
    }                                                                          \
    f32x4 acc0a = {0.f,0.f,0.f,0.f}, acc0b = {0.f,0.f,0.f,0.f};                \
    f32x4 acc1a = {0.f,0.f,0.f,0.f}, acc1b = {0.f,0.f,0.f,0.f};                \
    _Pragma("unroll")                                                          \
    for (int kt = 0; kt < KT; kt += 2) {                                       \
      bf16x8 a0 = *(const bf16x8*)&Abuf[cur][lc][kt * 32 + grp * 8];           \
      bf16x8 a1 = *(const bf16x8*)&Abuf[cur][lc][(kt + 1) * 32 + grp * 8];     \
      acc0a = __builtin_amdgcn_mfma_f32_16x16x32_bf16(a0, wf0[kt], acc0a, 0, 0, 0);     \
      acc1a = __builtin_amdgcn_mfma_f32_16x16x32_bf16(a0, wf1[kt], acc1a, 0, 0, 0);     \
      acc0b = __builtin_amdgcn_mfma_f32_16x16x32_bf16(a1, wf0[kt + 1], acc0b, 0, 0, 0); \
      acc1b = __builtin_amdgcn_mfma_f32_16x16x32_bf16(a1, wf1[kt + 1], acc1b, 0, 0, 0); \
    }                                                                          \
    f32x4 acc0 = acc0a + acc0b, acc1 = acc1a + acc1b;                          \
    float p0[4], p1[4];                                                        \
    if (rowv) {                                                                \
      _Pragma("unroll")                                                        \
      for (int r = 0; r < 4; ++r) {                                            \
        int lrow = grp * 4 + r;                                                \
        float2 xv = *(const float2*)&xbuf[lrow][(S) * 2];                      \
        float pre0 = acc0[r] + xv.x * wih00 + xv.y * wih10 + biasc0;           \
        float pre1 = acc1[r] + xv.x * wih01 + xv.y * wih11 + biasc1;           \
        float h0 = fmaxf(pre0, 0.f) + nsc0 * NBC[r].x;                         \
        float h1 = fmaxf(pre1, 0.f) + nsc1 * NBC[r].y;                         \
        p0[r] = h0 * wo00 + h1 * wo01;                                         \
        p1[r] = h0 * wo10 + h1 * wo11;                                         \
        uint32_t pk = (uint32_t)(uint16_t)f2bf(h0) |                           \
                      ((uint32_t)(uint16_t)f2bf(h1) << 16);                    \
        *(uint32_t*)&Abuf[nxt][lrow][c0] = pk;                                 \
      }                                                                        \
    } else {                                                                   \
      _Pragma("unroll")                                                        \
      for (int r = 0; r < 4; ++r) { p0[r] = 0.f; p1[r] = 0.f; }                \
    }                                                                          \
    /* reduce the 2-col partials across the 16 lanes sharing these rows */     \
    _Pragma("unroll")                                                          \
    for (int m = 1; m < 16; m <<= 1) {                                         \
      _Pragma("unroll")                                                        \
      for (int r = 0; r < 4; ++r) {                                            \
        p0[r] += __shfl_xor(p0[r], m);                                         \
        p1[r] += __shfl_xor(p1[r], m);                                         \
      }                                                                        \
    }                                                                          \
    if (lc == 0 && rowv) {                                                     \
      _Pragma("unroll")                                                        \
      for (int r = 0; r < 4; ++r) {                                            \
        part[cur][wave][grp * 4 + r][0] = p0[r];                               \
        part[cur][wave][grp * 4 + r][1] = p1[r];                               \
      }                                                                        \
    }                                                                          \
    __syncthreads();                                                           \
    if (tid < 16) {                                                            \
      int rr = tid >> 1, o = tid & 1;                                          \
      float v = o ? bout1 : bout0;                                             \
      _Pragma("unroll")                                                        \
      for (int w = 0; w < WAVES; ++w) v += part[cur][w][rr][o];                \
      outbuf[rr][(S) * 2 + o] = v;                                             \
    }                                                                          \
  }

  for (int s = 0; s < SEQ - 1; s += 2) {
    STEP(s, nbA, nbB);
    STEP(s + 1, nbB, nbA);
  }
  STEP(SEQ - 1, nbA, nbB);  // SEQ odd: last (even) step consumes nbA

#undef STEP

  __syncthreads();

  // coalesced flush of staged outputs
  for (int i = tid; i < RPW * SEQ * 2; i += NTH) {
    int r = i / (SEQ * 2), j = i % (SEQ * 2);
    out[(row0 + r) * (SEQ * 2) + j] = outbuf[r][j];
  }
}

extern "C" void kernel_launch(void* const* d_in, const int* in_sizes, int n_in,
                              void* d_out, int out_size, void* d_ws, size_t ws_size,
                              hipStream_t stream) {
  const float* xp     = (const float*)d_in[0];
  const float* noise  = (const float*)d_in[1];
  const float* W_ih   = (const float*)d_in[2];
  const float* b_ih   = (const float*)d_in[3];
  const float* W_hh   = (const float*)d_in[4];
  const float* b_hh   = (const float*)d_in[5];
  const float* W_out  = (const float*)d_in[6];
  const float* b_out  = (const float*)d_in[7];
  float* outp         = (float*)d_out;

  rnn_fused<<<dim3(2048 / RPW), dim3(NTH), 0, stream>>>(
      xp, noise, W_ih, b_ih, W_hh, b_hh, W_out, b_out, outp);
}

// Round 3
// 271.030 us; speedup vs baseline: 1.0993x; 1.0719x over previous
//
#include <hip/hip_runtime.h>
#include <stdint.h>

// VanillaRNN fused: B=2048,S=125,I=2,H=300,O=2
// h_t = relu(x_t@W_ih^T + b_ih + h_{t-1}@W_hh^T + b_hh) + 0.01*noise_t
// out = h_t @ W_out^T + b_out
//
// 256 WGs x 320 threads (5 waves); each WG owns 8 batch rows for all 125
// steps. Each wave owns 64 hidden columns mapped c = n0 + 4*lc + j, with
// W_hh^T fragments persistent in registers (160 VGPR). W_out occupies pad
// COLUMNS 300/301 of the N-dim, so step t's MFMA computes h_{t-1}@W_out^T
// for free (wave 4, lane 11) -> no cross-lane/cross-wave output reduce.
// Barrier = raw s_barrier + lgkmcnt(0) only: noise prefetch (register-
// private) stays in flight across barriers.

#define SEQ   125
#define HID   300
#define APAD  328     // Abuf row stride in shorts (16B-aligned rows)
#define KT    10
#define WAVES 5
#define NTH   (WAVES * 64)
#define RPW   8       // batch rows per WG

typedef __attribute__((ext_vector_type(8))) short bf16x8;
typedef __attribute__((ext_vector_type(4))) float f32x4;

__device__ __forceinline__ short f2bf(float f) {
  union { float f; uint32_t u; } v; v.f = f;
  uint32_t r = (v.u + 0x7fffu + ((v.u >> 16) & 1u)) >> 16;  // RNE
  return (short)r;
}

__device__ __forceinline__ uint32_t cvt_pk_bf16(float lo, float hi) {
  uint32_t r;
  asm("v_cvt_pk_bf16_f32 %0, %1, %2" : "=v"(r) : "v"(lo), "v"(hi));
  return r;
}

__device__ __forceinline__ void wg_barrier() {
  // lgkmcnt(0): own ds_reads complete (WAR-safe) + own ds_writes visible
  // (RAW-safe). Deliberately NOT vmcnt: noise loads are register-private.
  asm volatile("s_waitcnt lgkmcnt(0)" ::: "memory");
  __builtin_amdgcn_s_barrier();
}

__global__ __launch_bounds__(NTH, 2) void rnn_fused(
    const float* __restrict__ x,      // [2048,125,2]
    const float* __restrict__ noise,  // [2048,125,300]
    const float* __restrict__ W_ih,   // [300,2]
    const float* __restrict__ b_ih,   // [300]
    const float* __restrict__ W_hh,   // [300,300]
    const float* __restrict__ b_hh,   // [300]
    const float* __restrict__ W_out,  // [2,300]
    const float* __restrict__ b_out,  // [2]
    float* __restrict__ out)          // [2048,125,2]
{
  __shared__ __align__(16) short Abuf[2][16][APAD];  // h (bf16), dbuf; rows 8..15 stay 0
  __shared__ float xbuf[RPW][SEQ * 2];               // staged x
  __shared__ float outbuf[RPW][SEQ * 2];             // staged outputs

  const int tid  = threadIdx.x;
  const int wave = tid >> 6;
  const int lane = tid & 63;
  const int grp  = lane >> 4;     // 0..3
  const int lc   = lane & 15;     // 0..15
  const int row0 = blockIdx.x * RPW;
  const int n0   = wave << 6;     // wave's 64-col base
  const int c0   = n0 + 4 * lc;   // this lane's 4 cols: c0..c0+3
  const bool vld  = (c0 < HID);   // whole-lane col validity (c0 mult of 4)
  const bool rowv = (grp < 2);    // rows grp*4+r valid (RPW=8)

  // zero both h buffers (pad cols/rows harmless or stay 0)
  for (int i = tid; i < 2 * 16 * APAD / 2; i += NTH)
    ((uint32_t*)Abuf)[i] = 0u;
  // stage x
  for (int i = tid; i < RPW * SEQ * 2; i += NTH) {
    int r = i / (SEQ * 2), j = i % (SEQ * 2);
    xbuf[r][j] = x[(row0 + r) * (SEQ * 2) + j];
  }

  // per-lane column constants (j = 0..3, col c = c0 + j)
  float wih0[4], wih1[4], biasc[4];
#pragma unroll
  for (int j = 0; j < 4; ++j) {
    int c = c0 + j;
    bool v = (c < HID);
    int cc = v ? c : 0;
    wih0[j]  = v ? W_ih[cc * 2 + 0] : 0.f;
    wih1[j]  = v ? W_ih[cc * 2 + 1] : 0.f;
    biasc[j] = v ? (b_ih[cc] + b_hh[cc]) : 0.f;
  }
  const float nsc = vld ? 0.01f : 0.f;
  const float bout0 = b_out[0], bout1 = b_out[1];

  // persistent B fragments: wf[j][kt], lane supplies col c0+j at MFMA n=lc.
  // cols 300/301 carry W_out rows 0/1 (the fused output projection).
  bf16x8 wf[4][KT];
#pragma unroll
  for (int j = 0; j < 4; ++j) {
    int c = c0 + j;
#pragma unroll
    for (int kt = 0; kt < KT; ++kt) {
      bf16x8 f;
#pragma unroll
      for (int e = 0; e < 8; ++e) {
        int k = kt * 32 + grp * 8 + e;
        float v = 0.f;
        if (k < HID) {
          if (c < HID)            v = W_hh[c * HID + k];
          else if (c == HID)      v = W_out[k];
          else if (c == HID + 1)  v = W_out[HID + k];
        }
        f[e] = f2bf(v);
      }
      wf[j][kt] = f;
    }
  }

  // noise addressing (clamped for invalid lanes; guarded by vld anyway)
  const int cc0 = vld ? c0 : 0;
  int noff[4];
#pragma unroll
  for (int r = 0; r < 4; ++r) {
    int b = row0 + (grp & 1) * 4 + r;
    noff[r] = b * (SEQ * HID) + cc0 + HID;  // pre-advanced to s=1
  }

  // preload noise for s=0; zero-init so invalid lanes contribute exact 0
  float4 nbA[4] = {}, nbB[4] = {};
  if (rowv && vld) {
#pragma unroll
    for (int r = 0; r < 4; ++r)
      nbA[r] = *(const float4*)&noise[noff[r] - HID];
  }

  __syncthreads();

  // Iteration S (0..125): MFMA on h_{S-1}; extract out[S-1] (S>=1);
  // epilogue builds h_S (S<125). 126 iterations total.
#define ITER(S, NBC, NBN)                                                      \
  {                                                                            \
    const int cur = (S) & 1, nxt = cur ^ 1;                                    \
    if (rowv && vld && (S) + 1 < SEQ) {                                        \
      _Pragma("unroll")                                                        \
      for (int r = 0; r < 4; ++r)                                              \
        NBN[r] = *(const float4*)&noise[noff[r]];                              \
    }                                                                          \
    f32x4 ac0 = {0.f,0.f,0.f,0.f}, ac1 = {0.f,0.f,0.f,0.f};                    \
    f32x4 ac2 = {0.f,0.f,0.f,0.f}, ac3 = {0.f,0.f,0.f,0.f};                    \
    _Pragma("unroll")                                                          \
    for (int kt = 0; kt < KT; ++kt) {                                          \
      bf16x8 a = *(const bf16x8*)&Abuf[cur][lc][kt * 32 + grp * 8];            \
      ac0 = __builtin_amdgcn_mfma_f32_16x16x32_bf16(a, wf[0][kt], ac0, 0,0,0); \
      ac1 = __builtin_amdgcn_mfma_f32_16x16x32_bf16(a, wf[1][kt], ac1, 0,0,0); \
      ac2 = __builtin_amdgcn_mfma_f32_16x16x32_bf16(a, wf[2][kt], ac2, 0,0,0); \
      ac3 = __builtin_amdgcn_mfma_f32_16x16x32_bf16(a, wf[3][kt], ac3, 0,0,0); \
    }                                                                          \
    if ((S) >= 1 && wave == 4 && lc == 11 && rowv) {                           \
      _Pragma("unroll")                                                        \
      for (int r = 0; r < 4; ++r) {                                            \
        outbuf[grp * 4 + r][((S) - 1) * 2 + 0] = ac0[r] + bout0;               \
        outbuf[grp * 4 + r][((S) - 1) * 2 + 1] = ac1[r] + bout1;               \
      }                                                                        \
    }                                                                          \
    if ((S) < SEQ) {                                                           \
      if (rowv) {                                                              \
        _Pragma("unroll")                                                      \
        for (int r = 0; r < 4; ++r) {                                          \
          int lrow = grp * 4 + r;                                              \
          float2 xv = *(const float2*)&xbuf[lrow][(S) * 2];                    \
          float h0 = fmaxf(ac0[r] + xv.x*wih0[0] + xv.y*wih1[0] + biasc[0], 0.f) + nsc * NBC[r].x; \
          float h1 = fmaxf(ac1[r] + xv.x*wih0[1] + xv.y*wih1[1] + biasc[1], 0.f) + nsc * NBC[r].y; \
          float h2 = fmaxf(ac2[r] + xv.x*wih0[2] + xv.y*wih1[2] + biasc[2], 0.f) + nsc * NBC[r].z; \
          float h3 = fmaxf(ac3[r] + xv.x*wih0[3] + xv.y*wih1[3] + biasc[3], 0.f) + nsc * NBC[r].w; \
          uint2 pk;                                                            \
          pk.x = cvt_pk_bf16(h0, h1);                                          \
          pk.y = cvt_pk_bf16(h2, h3);                                          \
          *(uint2*)&Abuf[nxt][lrow][c0] = pk;                                  \
        }                                                                      \
      }                                                                        \
      _Pragma("unroll")                                                        \
      for (int r = 0; r < 4; ++r) noff[r] += HID;                              \
      wg_barrier();                                                            \
    }                                                                          \
  }

  for (int sb = 0; sb < SEQ; sb += 2) {  // sb = 0,2,...,124 -> S = 0..125
    ITER(sb, nbA, nbB);
    ITER(sb + 1, nbB, nbA);
  }
#undef ITER

  __syncthreads();  // full drain once: outbuf visible to all

  // coalesced flush of staged outputs
  for (int i = tid; i < RPW * SEQ * 2; i += NTH) {
    int r = i / (SEQ * 2), j = i % (SEQ * 2);
    out[(row0 + r) * (SEQ * 2) + j] = outbuf[r][j];
  }
}

extern "C" void kernel_launch(void* const* d_in, const int* in_sizes, int n_in,
                              void* d_out, int out_size, void* d_ws, size_t ws_size,
                              hipStream_t stream) {
  const float* xp     = (const float*)d_in[0];
  const float* noise  = (const float*)d_in[1];
  const float* W_ih   = (const float*)d_in[2];
  const float* b_ih   = (const float*)d_in[3];
  const float* W_hh   = (const float*)d_in[4];
  const float* b_hh   = (const float*)d_in[5];
  const float* W_out  = (const float*)d_in[6];
  const float* b_out  = (const float*)d_in[7];
  float* outp         = (float*)d_out;

  rnn_fused<<<dim3(2048 / RPW), dim3(NTH), 0, stream>>>(
      xp, noise, W_ih, b_ih, W_hh, b_hh, W_out, b_out, outp);
}

// Round 5
// 192.400 us; speedup vs baseline: 1.5486x; 1.4087x over previous
//
#include <hip/hip_runtime.h>
#include <stdint.h>

// VanillaRNN fused: B=2048,S=125,I=2,H=300,O=2
// h_t = relu(x_t@W_ih^T + b_ih + h_{t-1}@W_hh^T + b_hh) + 0.01*noise_t
// out = h_t @ W_out^T + b_out
//
// 256 WGs x 640 threads (10 waves); each WG owns 8 batch rows for all 125
// steps. Each wave owns 32 hidden columns as even/odd pairs (c0=n0+2lc,
// c1=c0+1): wf = 2x10 frags = 80 VGPR -> total ~140 regs, UNDER the
// structural 170-reg cap (512 / 3-waves-per-SIMD), so W_hh truly persists
// in registers (R1-R4 all spilled: 5-wave shape capped at 256 < ~290 need;
// R3's WRITE_SIZE=63MB was spill write-back).
// W_out rides as pad COLUMNS 300/301 (wave 9, lane 6) -> no output reduce.
// Barriers are plain __syncthreads() -- raw s_barrier is not a compiler
// fence and caused R4's replay-timing race.

#define SEQ   125
#define HID   300
#define APAD  328     // Abuf row stride in shorts; 656B rows, 16B-aligned
#define KT    10
#define WAVES 10
#define NTH   (WAVES * 64)
#define RPW   8       // batch rows per WG

typedef __attribute__((ext_vector_type(8))) short bf16x8;
typedef __attribute__((ext_vector_type(4))) float f32x4;

__device__ __forceinline__ short f2bf(float f) {
  union { float f; uint32_t u; } v; v.f = f;
  uint32_t r = (v.u + 0x7fffu + ((v.u >> 16) & 1u)) >> 16;  // RNE
  return (short)r;
}

__device__ __forceinline__ uint32_t cvt_pk_bf16(float lo, float hi) {
  uint32_t r;
  asm("v_cvt_pk_bf16_f32 %0, %1, %2" : "=v"(r) : "v"(lo), "v"(hi));
  return r;
}

__global__ __launch_bounds__(NTH, 3) void rnn_fused(
    const float* __restrict__ x,      // [2048,125,2]
    const float* __restrict__ noise,  // [2048,125,300]
    const float* __restrict__ W_ih,   // [300,2]
    const float* __restrict__ b_ih,   // [300]
    const float* __restrict__ W_hh,   // [300,300]
    const float* __restrict__ b_hh,   // [300]
    const float* __restrict__ W_out,  // [2,300]
    const float* __restrict__ b_out,  // [2]
    float* __restrict__ out)          // [2048,125,2]
{
  __shared__ __align__(16) short Abuf[2][16][APAD];  // h (bf16), dbuf; rows 8..15 stay 0
  __shared__ float xbuf[RPW][SEQ * 2];               // staged x
  __shared__ float outbuf[RPW][SEQ * 2];             // staged outputs

  const int tid  = threadIdx.x;
  const int wave = tid >> 6;
  const int lane = tid & 63;
  const int grp  = lane >> 4;     // 0..3
  const int lc   = lane & 15;     // 0..15
  const int row0 = blockIdx.x * RPW;
  const int n0   = wave << 5;     // wave's 32-col base
  const int c0   = n0 + 2 * lc;   // even col
  const int c1   = c0 + 1;        // odd col
  const bool v0  = (c0 < HID), v1 = (c1 < HID);
  const bool rowv = (grp < 2);    // rows grp*4+r valid (RPW=8)

  // zero both h buffers (pad cols/rows harmless or stay 0)
  for (int i = tid; i < 2 * 16 * APAD / 2; i += NTH)
    ((uint32_t*)Abuf)[i] = 0u;
  // stage x
  for (int i = tid; i < RPW * SEQ * 2; i += NTH) {
    int r = i / (SEQ * 2), j = i % (SEQ * 2);
    xbuf[r][j] = x[(row0 + r) * (SEQ * 2) + j];
  }

  // per-lane column constants (zeroed for pad cols)
  const float wih00 = v0 ? W_ih[c0 * 2 + 0] : 0.f;
  const float wih10 = v0 ? W_ih[c0 * 2 + 1] : 0.f;
  const float wih01 = v1 ? W_ih[c1 * 2 + 0] : 0.f;
  const float wih11 = v1 ? W_ih[c1 * 2 + 1] : 0.f;
  const float biasc0 = v0 ? (b_ih[c0] + b_hh[c0]) : 0.f;
  const float biasc1 = v1 ? (b_ih[c1] + b_hh[c1]) : 0.f;
  const float nsc = v0 ? 0.01f : 0.f;   // c0 valid => c1 valid or c1==300 (w9/lc6: nsc irrelevant, see below)
  const float bout0 = b_out[0], bout1 = b_out[1];

  // persistent B fragments: lane supplies cols c0 (wf0) / c1 (wf1) at MFMA n=lc.
  // cols 300/301 carry W_out rows 0/1 (fused output projection).
  bf16x8 wf0[KT], wf1[KT];
#pragma unroll
  for (int kt = 0; kt < KT; ++kt) {
    bf16x8 f0, f1;
#pragma unroll
    for (int e = 0; e < 8; ++e) {
      int k = kt * 32 + grp * 8 + e;
      float a = 0.f, b = 0.f;
      if (k < HID) {
        if (c0 < HID)           a = W_hh[c0 * HID + k];
        else if (c0 == HID)     a = W_out[k];
        if (c1 < HID)           b = W_hh[c1 * HID + k];
        else if (c1 == HID)     b = W_out[k];
        else if (c1 == HID + 1) b = W_out[HID + k];
      }
      f0[e] = f2bf(a);
      f1[e] = f2bf(b);
    }
    wf0[kt] = f0; wf1[kt] = f1;
  }

  // noise addressing; clamped col for invalid lanes (loads guarded anyway)
  const int cc0 = v0 ? c0 : 0;
  int noff[4];
#pragma unroll
  for (int r = 0; r < 4; ++r) {
    int b = row0 + (grp & 1) * 4 + r;
    noff[r] = b * (SEQ * HID) + cc0 + HID;  // pre-advanced to s=1
  }

  // preload noise for s=0 (pair of adjacent cols -> float2)
  float2 nbA[4] = {}, nbB[4] = {};
  if (rowv && v0 && v1) {
#pragma unroll
    for (int r = 0; r < 4; ++r)
      nbA[r] = *(const float2*)&noise[noff[r] - HID];
  }

  __syncthreads();

  // Iteration S (0..125): MFMA on h_{S-1}; extract out[S-1] (S>=1);
  // epilogue builds h_S (S<125). 126 iterations total.
#define ITER(S, NBC, NBN)                                                      \
  {                                                                            \
    const int cur = (S) & 1, nxt = cur ^ 1;                                    \
    if (rowv && v0 && v1 && (S) + 1 < SEQ) {                                   \
      _Pragma("unroll")                                                        \
      for (int r = 0; r < 4; ++r)                                              \
        NBN[r] = *(const float2*)&noise[noff[r]];                              \
    }                                                                          \
    f32x4 ac0 = {0.f,0.f,0.f,0.f}, ac1 = {0.f,0.f,0.f,0.f};                    \
    _Pragma("unroll")                                                          \
    for (int kt = 0; kt < KT; ++kt) {                                          \
      bf16x8 a = *(const bf16x8*)&Abuf[cur][lc][kt * 32 + grp * 8];            \
      ac0 = __builtin_amdgcn_mfma_f32_16x16x32_bf16(a, wf0[kt], ac0, 0,0,0);   \
      ac1 = __builtin_amdgcn_mfma_f32_16x16x32_bf16(a, wf1[kt], ac1, 0,0,0);   \
    }                                                                          \
    if ((S) >= 1 && wave == 9 && lc == 6 && rowv) {                            \
      _Pragma("unroll")                                                        \
      for (int r = 0; r < 4; ++r) {                                            \
        outbuf[grp * 4 + r][((S) - 1) * 2 + 0] = ac0[r] + bout0;               \
        outbuf[grp * 4 + r][((S) - 1) * 2 + 1] = ac1[r] + bout1;               \
      }                                                                        \
    }                                                                          \
    if ((S) < SEQ) {                                                           \
      if (rowv) {                                                              \
        _Pragma("unroll")                                                      \
        for (int r = 0; r < 4; ++r) {                                          \
          int lrow = grp * 4 + r;                                              \
          float2 xv = *(const float2*)&xbuf[lrow][(S) * 2];                    \
          float h0 = fmaxf(ac0[r] + xv.x*wih00 + xv.y*wih10 + biasc0, 0.f) + nsc * NBC[r].x; \
          float h1 = fmaxf(ac1[r] + xv.x*wih01 + xv.y*wih11 + biasc1, 0.f) + nsc * NBC[r].y; \
          *(uint32_t*)&Abuf[nxt][lrow][c0] = cvt_pk_bf16(h0, h1);              \
        }                                                                      \
      }                                                                        \
      _Pragma("unroll")                                                        \
      for (int r = 0; r < 4; ++r) noff[r] += HID;                              \
      __syncthreads();                                                         \
    }                                                                          \
  }

  for (int sb = 0; sb < SEQ; sb += 2) {  // sb = 0,2,...,124 -> S = 0..125
    ITER(sb, nbA, nbB);
    ITER(sb + 1, nbB, nbA);
  }
#undef ITER

  __syncthreads();  // outbuf visible to all

  // coalesced flush of staged outputs
  for (int i = tid; i < RPW * SEQ * 2; i += NTH) {
    int r = i / (SEQ * 2), j = i % (SEQ * 2);
    out[(row0 + r) * (SEQ * 2) + j] = outbuf[r][j];
  }
}

extern "C" void kernel_launch(void* const* d_in, const int* in_sizes, int n_in,
                              void* d_out, int out_size, void* d_ws, size_t ws_size,
                              hipStream_t stream) {
  const float* xp     = (const float*)d_in[0];
  const float* noise  = (const float*)d_in[1];
  const float* W_ih   = (const float*)d_in[2];
  const float* b_ih   = (const float*)d_in[3];
  const float* W_hh   = (const float*)d_in[4];
  const float* b_hh   = (const float*)d_in[5];
  const float* W_out  = (const float*)d_in[6];
  const float* b_out  = (const float*)d_in[7];
  float* outp         = (float*)d_out;

  rnn_fused<<<dim3(2048 / RPW), dim3(NTH), 0, stream>>>(
      xp, noise, W_ih, b_ih, W_hh, b_hh, W_out, b_out, outp);
}